// Round 13
// baseline (181.012 us; speedup 1.0000x reference)
//
#include <hip/hip_runtime.h>
#include <hip/hip_bf16.h>

typedef unsigned short ushort_t;
typedef short bf16x8 __attribute__((ext_vector_type(8)));
typedef float f32x4 __attribute__((ext_vector_type(4)));

#define B_ 8
#define N_ 128
#define E_ 16256           // 128*127
#define BE 130048          // 8*E_

__device__ __forceinline__ float eluf(float x) {
    return x > 0.0f ? x : __expf(x) - 1.0f;
}
__device__ __forceinline__ ushort_t f2bf(float f) {
    union { float f; unsigned u; } v; v.f = f;
    return (ushort_t)((v.u + 0x7fffu + ((v.u >> 16) & 1u)) >> 16);
}
__device__ __forceinline__ float bf2f(ushort_t h) {
    union { unsigned u; float f; } v; v.u = ((unsigned)h) << 16;
    return v.f;
}

// async global->LDS, 16B per lane; LDS dest = wave-uniform base + lane*16.
__device__ __forceinline__ void glds16(void* lds, const void* g) {
    __builtin_amdgcn_global_load_lds(
        (const __attribute__((address_space(1))) unsigned int*)g,
        (__attribute__((address_space(3))) unsigned int*)lds, 16, 0, 0);
}

// ---------------- weight image builders ----------------
// img64: chunk c (64k x 256n = 32KB): img[c][n][u'][j] = w[c*64 + (u'^(n&7))*8 + j][n]
__device__ __forceinline__ void img64_elem(const float* __restrict__ w,
                                           ushort_t* __restrict__ img, int i) {
    int c = i >> 14;  int r = i & 16383;
    int n = r >> 6;   int wdx = r & 63;
    int up = wdx >> 3, j = wdx & 7;
    int u = up ^ (n & 7);
    int k = c * 64 + u * 8 + j;
    img[i] = f2bf(w[(size_t)k * 256 + n]);
}
// img128: chunk c (128k x 256n = 64KB): img[c][n][u'][j] = w[c*128 + (u'^(n&15))*8 + j][n]
__device__ __forceinline__ void img128_elem(const float* __restrict__ w,
                                            ushort_t* __restrict__ img, int i) {
    int c = i >> 15;  int r = i & 32767;
    int n = r >> 7;   int wdx = r & 127;
    int up = wdx >> 3, j = wdx & 7;
    int u = up ^ (n & 15);
    int k = c * 128 + u * 8 + j;
    img[i] = f2bf(w[(size_t)k * 256 + n]);
}
// img128 with K zero-padding
__device__ __forceinline__ void img128_pad(const float* __restrict__ w,
                                           ushort_t* __restrict__ img, int i, int Kreal) {
    int c = i >> 15;  int r = i & 32767;
    int n = r >> 7;   int wdx = r & 127;
    int up = wdx >> 3, j = wdx & 7;
    int u = up ^ (n & 15);
    int k = c * 128 + u * 8 + j;
    img[i] = (k < Kreal) ? f2bf(w[(size_t)k * 256 + n]) : (ushort_t)0;
}

// 11 images x 65536 elems (node imgs img128; edge wA/wB/wC img64)
__global__ __launch_bounds__(256) void wprep_all(
    const float* __restrict__ n1w1, ushort_t* __restrict__ s0,
    const float* __restrict__ n1w2, ushort_t* __restrict__ s1,
    const float* __restrict__ e1w1, ushort_t* __restrict__ s2, ushort_t* __restrict__ s3,
    const float* __restrict__ n2w1, ushort_t* __restrict__ s4,
    const float* __restrict__ n2w2, ushort_t* __restrict__ s5,
    const float* __restrict__ e2w1, ushort_t* __restrict__ s6, ushort_t* __restrict__ s7,
    ushort_t* __restrict__ s8,
    const float* __restrict__ e1w2, ushort_t* __restrict__ s9,
    const float* __restrict__ e2w2, ushort_t* __restrict__ s10)
{
    int gid = blockIdx.x * 256 + threadIdx.x;
    int img = gid >> 16, r = gid & 65535;
    switch (img) {
        case 0:  img128_pad (n1w1, s0, r, 196); break;
        case 1:  img128_elem(n1w2, s1, r); break;
        case 2:  img128_elem(e1w1, s2, r); break;
        case 3:  img128_elem(e1w1 + 65536, s3, r); break;
        case 4:  img128_elem(n2w1, s4, r); break;
        case 5:  img128_elem(n2w2, s5, r); break;
        case 6:  img128_elem(e2w1, s6, r); break;
        case 7:  img128_elem(e2w1 + 65536, s7, r); break;
        case 8:  img64_elem (e2w1 + 131072, s8, r); break;   // W1x img64
        case 9:  img64_elem (e1w2, s9, r); break;            // wA img64
        default: img64_elem (e2w2, s10, r); break;           // wC img64
    }
}

// ---------------- fused node pipeline (MFMA): in -> h1 -> h -> P[1024][512] ----------------
// 32 blocks x 32 rows, 4 waves. LDS: A 32x512B XOR [0,16K), W ring 2x64K [16K,144K).
template<bool TWOIN>
__global__ __launch_bounds__(256, 1) void node_fused(
    const float* __restrict__ in0, const float* __restrict__ in1,
    const ushort_t* __restrict__ iw1, const float* __restrict__ b1,
    const ushort_t* __restrict__ iw2, const float* __restrict__ b2,
    const ushort_t* __restrict__ ipr, const ushort_t* __restrict__ ips,
    const float* __restrict__ bE,
    float* __restrict__ P)
{
    extern __shared__ char smem[];
    const int t = threadIdx.x;
    const int wid = t >> 6, lane = t & 63, lr = lane & 15, lg = lane >> 4;
    const int r0 = blockIdx.x * 32;

    float bias1[4], bias2[4], biasP[4];
    #pragma unroll
    for (int f = 0; f < 4; ++f) {
        int col = wid * 64 + f * 16 + lr;
        bias1[f] = b1[col];
        bias2[f] = b2[col];
        biasP[f] = 0.5f * bE[col];
    }

    f32x4 acc[2][4];
    #pragma unroll
    for (int m = 0; m < 2; ++m)
        #pragma unroll
        for (int f = 0; f < 4; ++f) acc[m][f] = f32x4{0.f, 0.f, 0.f, 0.f};

    auto stageW = [&](const ushort_t* img, int c, int p) {
        const char* src = (const char*)img + (size_t)c * 65536 + wid * 16384 + lane * 16;
        char* dst = smem + 16384 + p * 65536 + wid * 16384;
        #pragma unroll
        for (int it = 0; it < 16; ++it) glds16(dst + it * 1024, src + it * 1024);
    };

    int cc = 0;
    auto runGemm = [&](const ushort_t* img, const ushort_t* nimg) {
        for (int c = 0; c < 2; ++c) {
            const int p = cc & 1;
            if (c + 1 < 2)  stageW(img, 1, p ^ 1);
            else if (nimg)  stageW(nimg, 0, p ^ 1);
            const char* Wp = smem + 16384 + p * 65536;
            #pragma unroll
            for (int ks = 0; ks < 4; ++ks) {
                const int c32 = c * 4 + ks;
                bf16x8 a[2], b[4];
                const int qh = ((c32 * 4 + lg) ^ (lr & 7)) << 4;
                #pragma unroll
                for (int m = 0; m < 2; ++m)
                    a[m] = *(const bf16x8*)(smem + (m * 16 + lr) * 512 + qh);
                #pragma unroll
                for (int f = 0; f < 4; ++f)
                    b[f] = *(const bf16x8*)(Wp + (wid * 64 + f * 16 + lr) * 256 + (((ks * 4 + lg) ^ lr) << 4));
                #pragma unroll
                for (int m = 0; m < 2; ++m)
                    #pragma unroll
                    for (int f = 0; f < 4; ++f)
                        acc[m][f] = __builtin_amdgcn_mfma_f32_16x16x32_bf16(a[m], b[f], acc[m][f], 0, 0, 0);
            }
            __syncthreads();
            ++cc;
        }
    };

    auto transition = [&](const float* bv) {
        #pragma unroll
        for (int m = 0; m < 2; ++m)
            #pragma unroll
            for (int f = 0; f < 4; ++f) {
                const int col = wid * 64 + f * 16 + lr;
                const int ch = col >> 3;
                #pragma unroll
                for (int r = 0; r < 4; ++r) {
                    const int row = m * 16 + lg * 4 + r;
                    float v = eluf(acc[m][f][r] + bv[f]);
                    *(ushort_t*)(smem + row * 512 + ((ch ^ (row & 7)) << 4) + ((col & 7) << 1)) = f2bf(v);
                }
                acc[m][f] = f32x4{0.f, 0.f, 0.f, 0.f};
            }
        __syncthreads();
    };

    auto pwrite = [&](int half) {
        #pragma unroll
        for (int m = 0; m < 2; ++m)
            #pragma unroll
            for (int f = 0; f < 4; ++f) {
                const int col = wid * 64 + f * 16 + lr;
                #pragma unroll
                for (int r = 0; r < 4; ++r) {
                    const int row = m * 16 + lg * 4 + r;
                    P[(size_t)(r0 + row) * 512 + half * 256 + col] = acc[m][f][r] + biasP[f];
                }
                acc[m][f] = f32x4{0.f, 0.f, 0.f, 0.f};
            }
    };

    stageW(iw1, 0, 0);
    for (int idx = t; idx < 32 * 128; idx += 256) {
        const int row = idx >> 7;
        const int c0 = (idx & 127) * 2;
        float v0, v1;
        if (TWOIN) {
            const float* pa = in0 + (size_t)(r0 + row) * 256;
            const float* pb = in1 + (size_t)(r0 + row) * 256;
            v0 = pa[c0] + pb[c0];
            v1 = pa[c0 + 1] + pb[c0 + 1];
        } else {
            const float* pa = in0 + (size_t)(r0 + row) * 196;
            v0 = (c0 < 196) ? pa[c0] : 0.f;
            v1 = (c0 + 1 < 196) ? pa[c0 + 1] : 0.f;
        }
        unsigned u = (unsigned)f2bf(v0) | ((unsigned)f2bf(v1) << 16);
        const int ch = c0 >> 3;
        *(unsigned*)(smem + row * 512 + ((ch ^ (row & 7)) << 4) + (c0 & 7) * 2) = u;
    }
    __syncthreads();

    runGemm(iw1, iw2);
    transition(bias1);
    runGemm(iw2, ipr);
    transition(bias2);
    runGemm(ipr, ips);
    pwrite(0);
    runGemm(ips, nullptr);
    pwrite(1);
}

// ---------------- edge1': build -> GEMM(wA) -> {e1 + partials} -> GEMM(wB) -> G1 ----------------
// LDS: A-tile 256x512B XOR [0,128K), W single buffer 32KB [128K,160K). BK=64, 4 chunks/GEMM.
__global__ __launch_bounds__(512, 2) void edge1_kernel(
    const float* __restrict__ P1,
    const ushort_t* __restrict__ wAimg, const float* __restrict__ biasA,   // e1b2
    const ushort_t* __restrict__ wBimg,                                    // W1x img64
    ushort_t* __restrict__ G1,
    float* __restrict__ aggp0, float* __restrict__ aggp1)
{
    extern __shared__ char smem[];
    const int t = threadIdx.x;
    const int wid = t >> 6, lane = t & 63, lr = lane & 15, lg = lane >> 4;
    const int wr = wid >> 1, wc = wid & 1;
    const int blockRow = blockIdx.x * 256;

    auto stageW64 = [&](const ushort_t* img, int c) {
        const char* src = (const char*)img + (size_t)c * 32768 + wid * 4096 + lane * 16;
        char* dst = smem + 131072 + wid * 4096;
        #pragma unroll
        for (int it = 0; it < 4; ++it) glds16(dst + it * 1024, src + it * 1024);
    };

    float bA[8];
    #pragma unroll
    for (int f = 0; f < 8; ++f) bA[f] = biasA[wc * 128 + f * 16 + lr];

    f32x4 acc[4][8];
    #pragma unroll
    for (int m = 0; m < 4; ++m)
        #pragma unroll
        for (int f = 0; f < 8; ++f) acc[m][f] = f32x4{0.f, 0.f, 0.f, 0.f};

    // ---- build A = elu(P1r + P1s): coalesced, XOR LDS layout ----
    #pragma unroll 4
    for (int j = 0; j < 32; ++j) {
        const int row = wid * 32 + j;
        const int rg = blockRow + row;
        const int b = rg / E_; const int e = rg - b * E_;
        const int rcv = e / 127; const int kk = e - rcv * 127;
        const int snd = kk + (kk >= rcv ? 1 : 0);
        const float4 vr = *(const float4*)(P1 + (size_t)(b * N_ + rcv) * 512 + lane * 4);
        const float4 vs = *(const float4*)(P1 + (size_t)(b * N_ + snd) * 512 + 256 + lane * 4);
        unsigned u0 = (unsigned)f2bf(eluf(vr.x + vs.x)) | ((unsigned)f2bf(eluf(vr.y + vs.y)) << 16);
        unsigned u1 = (unsigned)f2bf(eluf(vr.z + vs.z)) | ((unsigned)f2bf(eluf(vr.w + vs.w)) << 16);
        const int byte = row * 512 + ((((lane >> 1) ^ (row & 7))) << 4) + (lane & 1) * 8;
        *(uint2*)(smem + byte) = make_uint2(u0, u1);
    }

    // ---- GEMM A: hid1 @ wA, 4 chunks BK=64, single-buffered ----
    for (int c = 0; c < 4; ++c) {
        stageW64(wAimg, c);
        __syncthreads();                 // drain stage (+ c==0: publishes build)
        const char* Wp = smem + 131072;
        #pragma unroll
        for (int ks = 0; ks < 2; ++ks) {
            const int kk = c * 2 + ks;
            bf16x8 a[4], b[8];
            const int qh = ((kk * 4 + lg) ^ (lr & 7)) << 4;
            const int sb = ((ks * 4 + lg) ^ (lr & 7)) << 4;
            #pragma unroll
            for (int m = 0; m < 4; ++m)
                a[m] = *(const bf16x8*)(smem + (wr * 64 + m * 16 + lr) * 512 + qh);
            #pragma unroll
            for (int f = 0; f < 8; ++f)
                b[f] = *(const bf16x8*)(Wp + (wc * 128 + f * 16 + lr) * 128 + sb);
            #pragma unroll
            for (int m = 0; m < 4; ++m)
                #pragma unroll
                for (int f = 0; f < 8; ++f)
                    acc[m][f] = __builtin_amdgcn_mfma_f32_16x16x32_bf16(a[m], b[f], acc[m][f], 0, 0, 0);
        }
        __syncthreads();                 // protect W buffer before next stage
    }

    // ---- transition: e1 = elu(acc + bA) -> A-tile (XOR) + segment partials ----
    const int gR0 = blockRow + wr * 64;
    const int sFirst = gR0 / 127;
    const int bk = 127 - (gR0 - sFirst * 127);
    float s0[8], s1[8];
    #pragma unroll
    for (int f = 0; f < 8; ++f) { s0[f] = 0.f; s1[f] = 0.f; }
    #pragma unroll
    for (int m = 0; m < 4; ++m)
        #pragma unroll
        for (int f = 0; f < 8; ++f) {
            const int col = wc * 128 + f * 16 + lr;
            const int ch = col >> 3;
            #pragma unroll
            for (int r = 0; r < 4; ++r) {
                const int rowL = m * 16 + lg * 4 + r;
                const int row = wr * 64 + rowL;
                float v = eluf(acc[m][f][r] + bA[f]);
                *(ushort_t*)(smem + row * 512 + ((ch ^ (row & 7)) << 4) + ((col & 7) << 1)) = f2bf(v);
                if (rowL < bk) s0[f] += v; else s1[f] += v;
            }
            acc[m][f] = f32x4{0.f, 0.f, 0.f, 0.f};
        }
    #pragma unroll
    for (int f = 0; f < 8; ++f) {
        s0[f] += __shfl_xor(s0[f], 16); s0[f] += __shfl_xor(s0[f], 32);
        s1[f] += __shfl_xor(s1[f], 16); s1[f] += __shfl_xor(s1[f], 32);
    }
    float* pt = (float*)(smem + 131072);   // wA buffer dead
    if (lg == 0) {
        #pragma unroll
        for (int f = 0; f < 8; ++f) {
            pt[(wid * 2 + 0) * 128 + f * 16 + lr] = s0[f];
            pt[(wid * 2 + 1) * 128 + f * 16 + lr] = s1[f];
        }
    }
    __syncthreads();
    {
        const int S0 = blockRow / 127;
        const int last = (blockRow + 255) / 127;
        const int cnt = last - S0 + 1;
        for (int task = t; task < cnt * 256; task += 512) {
            const int k = task >> 8;
            const int col = task & 255;
            const int sigma = S0 + k;
            const int wcq = col >> 7, c128 = col & 127;
            float sum = 0.f;
            #pragma unroll
            for (int w2r = 0; w2r < 4; ++w2r) {
                int sf = (blockRow + w2r * 64) / 127;
                int jj = sigma - sf;
                if (jj == 0 || jj == 1)
                    sum += pt[((w2r * 2 + wcq) * 2 + jj) * 128 + c128];
            }
            const bool startIn = (127 * sigma >= blockRow);
            const bool endIn = (127 * sigma + 127 <= blockRow + 256);
            if (startIn) {
                aggp0[(size_t)sigma * 256 + col] = sum;
                if (endIn) aggp1[(size_t)sigma * 256 + col] = 0.f;
            } else {
                aggp1[(size_t)sigma * 256 + col] = sum;
            }
        }
    }
    __syncthreads();   // pt reads done before GEMM-B stages overwrite

    // ---- GEMM B: e1 @ W1x, 4 chunks BK=64, single-buffered ----
    for (int c = 0; c < 4; ++c) {
        stageW64(wBimg, c);
        __syncthreads();
        const char* Wp = smem + 131072;
        #pragma unroll
        for (int ks = 0; ks < 2; ++ks) {
            const int kk = c * 2 + ks;
            bf16x8 a[4], b[8];
            const int qh = ((kk * 4 + lg) ^ (lr & 7)) << 4;
            const int sb = ((ks * 4 + lg) ^ (lr & 7)) << 4;
            #pragma unroll
            for (int m = 0; m < 4; ++m)
                a[m] = *(const bf16x8*)(smem + (wr * 64 + m * 16 + lr) * 512 + qh);
            #pragma unroll
            for (int f = 0; f < 8; ++f)
                b[f] = *(const bf16x8*)(Wp + (wc * 128 + f * 16 + lr) * 128 + sb);
            #pragma unroll
            for (int m = 0; m < 4; ++m)
                #pragma unroll
                for (int f = 0; f < 8; ++f)
                    acc[m][f] = __builtin_amdgcn_mfma_f32_16x16x32_bf16(a[m], b[f], acc[m][f], 0, 0, 0);
        }
        __syncthreads();
    }

    // ---- epilogue: G1 = acc (raw, bf16) via slice -> coalesced stores ----
    char* slice = smem + wid * 16384;
    #pragma unroll
    for (int m = 0; m < 4; ++m)
        #pragma unroll
        for (int f = 0; f < 8; ++f) {
            const int col = f * 16 + lr;
            const int cch = col >> 3;
            #pragma unroll
            for (int r = 0; r < 4; ++r) {
                const int rowL = m * 16 + lg * 4 + r;
                *(ushort_t*)(slice + rowL * 256 + ((cch ^ (rowL & 7)) << 4) + ((col & 7) << 1)) =
                    f2bf(acc[m][f][r]);
            }
        }
    asm volatile("s_waitcnt lgkmcnt(0)" ::: "memory");
    #pragma unroll
    for (int it = 0; it < 16; ++it) {
        const int q = it * 64 + lane;
        const int row = q >> 4, ccp = q & 15;
        bf16x8 v = *(const bf16x8*)(slice + row * 256 + (ccp << 4));
        const int cch = ccp ^ (row & 7);
        const int grow = blockRow + wr * 64 + row;
        *(bf16x8*)(G1 + (size_t)grow * 256 + wc * 128 + cch * 8) = v;
    }
}

// ---------------- edge2': build hid2 = elu(G1 + P2r + P2s) -> GEMM(wC) -> project ----------------
// LDS: A-tile 256x512B XOR [0,128K), wC single buffer 32KB [128K,160K). BK=64.
__global__ __launch_bounds__(512, 2) void edge2_kernel(
    const ushort_t* __restrict__ G1, const float* __restrict__ P2,
    const ushort_t* __restrict__ wCimg, const float* __restrict__ bC,
    const float* __restrict__ ow, const float* __restrict__ ob,
    float* __restrict__ out)
{
    extern __shared__ char smem[];
    const int t = threadIdx.x;
    const int wid = t >> 6, lane = t & 63, lr = lane & 15, lg = lane >> 4;
    const int wr = wid >> 1, wc = wid & 1;
    const int blockRow = blockIdx.x * 256;

    auto stageW64 = [&](int c) {
        const char* src = (const char*)wCimg + (size_t)c * 32768 + wid * 4096 + lane * 16;
        char* dst = smem + 131072 + wid * 4096;
        #pragma unroll
        for (int it = 0; it < 4; ++it) glds16(dst + it * 1024, src + it * 1024);
    };

    float biasC[8];
    #pragma unroll
    for (int f = 0; f < 8; ++f) biasC[f] = bC[wc * 128 + f * 16 + lr];

    f32x4 acc[4][8];
    #pragma unroll
    for (int m = 0; m < 4; ++m)
        #pragma unroll
        for (int f = 0; f < 8; ++f) acc[m][f] = f32x4{0.f, 0.f, 0.f, 0.f};

    // ---- build: hid2 = elu(G1 + P2r + P2s), coalesced, XOR LDS layout ----
    #pragma unroll 4
    for (int j = 0; j < 32; ++j) {
        const int row = wid * 32 + j;
        const int rg = blockRow + row;
        const int b = rg / E_; const int e = rg - b * E_;
        const int rcv = e / 127; const int kk = e - rcv * 127;
        const int snd = kk + (kk >= rcv ? 1 : 0);
        const ushort4 g4 = *(const ushort4*)(G1 + (size_t)rg * 256 + lane * 4);
        const float4 vr = *(const float4*)(P2 + (size_t)(b * N_ + rcv) * 512 + lane * 4);
        const float4 vs = *(const float4*)(P2 + (size_t)(b * N_ + snd) * 512 + 256 + lane * 4);
        unsigned u0 = (unsigned)f2bf(eluf(bf2f(g4.x) + vr.x + vs.x))
                    | ((unsigned)f2bf(eluf(bf2f(g4.y) + vr.y + vs.y)) << 16);
        unsigned u1 = (unsigned)f2bf(eluf(bf2f(g4.z) + vr.z + vs.z))
                    | ((unsigned)f2bf(eluf(bf2f(g4.w) + vr.w + vs.w)) << 16);
        const int byte = row * 512 + ((((lane >> 1) ^ (row & 7))) << 4) + (lane & 1) * 8;
        *(uint2*)(smem + byte) = make_uint2(u0, u1);
    }

    // ---- GEMM: hid2 @ W2e2, 4 chunks BK=64, single-buffered ----
    for (int c = 0; c < 4; ++c) {
        stageW64(c);
        __syncthreads();
        const char* Wp = smem + 131072;
        #pragma unroll
        for (int ks = 0; ks < 2; ++ks) {
            const int kk = c * 2 + ks;
            bf16x8 a[4], b[8];
            const int qh = ((kk * 4 + lg) ^ (lr & 7)) << 4;
            const int sb = ((ks * 4 + lg) ^ (lr & 7)) << 4;
            #pragma unroll
            for (int m = 0; m < 4; ++m)
                a[m] = *(const bf16x8*)(smem + (wr * 64 + m * 16 + lr) * 512 + qh);
            #pragma unroll
            for (int f = 0; f < 8; ++f)
                b[f] = *(const bf16x8*)(Wp + (wc * 128 + f * 16 + lr) * 128 + sb);
            #pragma unroll
            for (int m = 0; m < 4; ++m)
                #pragma unroll
                for (int f = 0; f < 8; ++f)
                    acc[m][f] = __builtin_amdgcn_mfma_f32_16x16x32_bf16(a[m], b[f], acc[m][f], 0, 0, 0);
        }
        __syncthreads();
    }

    // ---- epilogue: fused projection to [row][2] ----
    float ow0[8], ow1[8];
    #pragma unroll
    for (int f = 0; f < 8; ++f) {
        int col = wc * 128 + f * 16 + lr;
        ow0[f] = ow[col * 2 + 0];
        ow1[f] = ow[col * 2 + 1];
    }
    float s0[4][4], s1[4][4];
    #pragma unroll
    for (int m = 0; m < 4; ++m)
        #pragma unroll
        for (int r = 0; r < 4; ++r) { s0[m][r] = 0.f; s1[m][r] = 0.f; }
    #pragma unroll
    for (int m = 0; m < 4; ++m)
        #pragma unroll
        for (int f = 0; f < 8; ++f)
            #pragma unroll
            for (int r = 0; r < 4; ++r) {
                float v = eluf(acc[m][f][r] + biasC[f]);
                s0[m][r] = fmaf(v, ow0[f], s0[m][r]);
                s1[m][r] = fmaf(v, ow1[f], s1[m][r]);
            }
    #pragma unroll
    for (int msk = 1; msk <= 8; msk <<= 1)
        #pragma unroll
        for (int m = 0; m < 4; ++m)
            #pragma unroll
            for (int r = 0; r < 4; ++r) {
                s0[m][r] += __shfl_xor(s0[m][r], msk);
                s1[m][r] += __shfl_xor(s1[m][r], msk);
            }
    float* part = (float*)smem;
    if (lr == 0) {
        #pragma unroll
        for (int m = 0; m < 4; ++m)
            #pragma unroll
            for (int r = 0; r < 4; ++r) {
                const int row = wr * 64 + m * 16 + lg * 4 + r;
                part[(row * 2 + 0) * 2 + wc] = s0[m][r];
                part[(row * 2 + 1) * 2 + wc] = s1[m][r];
            }
    }
    __syncthreads();
    const int row = t >> 1, chn = t & 1;
    float val = part[(row * 2 + chn) * 2 + 0] + part[(row * 2 + chn) * 2 + 1] + ob[chn];
    out[(size_t)(blockRow + row) * 2 + chn] = val;
}

extern "C" void kernel_launch(void* const* d_in, const int* in_sizes, int n_in,
                              void* d_out, int out_size, void* d_ws, size_t ws_size,
                              hipStream_t stream)
{
    const float* x    = (const float*)d_in[0];
    const float* n1w1 = (const float*)d_in[3];
    const float* n1b1 = (const float*)d_in[4];
    const float* n1w2 = (const float*)d_in[5];
    const float* n1b2 = (const float*)d_in[6];
    const float* e1w1 = (const float*)d_in[7];
    const float* e1b1 = (const float*)d_in[8];
    const float* e1w2 = (const float*)d_in[9];
    const float* e1b2 = (const float*)d_in[10];
    const float* n2w1 = (const float*)d_in[11];
    const float* n2b1 = (const float*)d_in[12];
    const float* n2w2 = (const float*)d_in[13];
    const float* n2b2 = (const float*)d_in[14];
    const float* e2w1 = (const float*)d_in[15];
    const float* e2b1 = (const float*)d_in[16];
    const float* e2w2 = (const float*)d_in[17];
    const float* e2b2 = (const float*)d_in[18];
    const float* ow   = (const float*)d_in[19];
    const float* ob   = (const float*)d_in[20];

    char* ws = (char*)d_ws;
    const size_t KB = 1024;
    ushort_t* i_n1w1 = (ushort_t*)(ws + 0 * 128 * KB);
    ushort_t* i_n1w2 = (ushort_t*)(ws + 1 * 128 * KB);
    ushort_t* i_p1r  = (ushort_t*)(ws + 2 * 128 * KB);
    ushort_t* i_p1s  = (ushort_t*)(ws + 3 * 128 * KB);
    ushort_t* i_n2w1 = (ushort_t*)(ws + 4 * 128 * KB);
    ushort_t* i_n2w2 = (ushort_t*)(ws + 5 * 128 * KB);
    ushort_t* i_p2r  = (ushort_t*)(ws + 6 * 128 * KB);
    ushort_t* i_p2s  = (ushort_t*)(ws + 7 * 128 * KB);
    ushort_t* wB     = (ushort_t*)(ws + 8 * 128 * KB);
    ushort_t* wA     = (ushort_t*)(ws + 9 * 128 * KB);
    ushort_t* wC     = (ushort_t*)(ws + 10 * 128 * KB);
    float*    P1    = (float*)(ws + 1536 * KB);            // 2MB [1024][512]
    float*    P2    = (float*)(ws + 1536 * KB + (2u << 20));
    float*    aggp0 = (float*)(ws + 1536 * KB + (4u << 20));
    float*    aggp1 = (float*)(ws + 1536 * KB + (5u << 20));
    ushort_t* G1    = (ushort_t*)(ws + 1536 * KB + (6u << 20)); // 66.6MB [BE][256] bf16

    float* out = (float*)d_out;

    hipFuncSetAttribute((const void*)node_fused<false>,
                        hipFuncAttributeMaxDynamicSharedMemorySize, 147456);
    hipFuncSetAttribute((const void*)node_fused<true>,
                        hipFuncAttributeMaxDynamicSharedMemorySize, 147456);
    hipFuncSetAttribute((const void*)edge1_kernel,
                        hipFuncAttributeMaxDynamicSharedMemorySize, 163840);
    hipFuncSetAttribute((const void*)edge2_kernel,
                        hipFuncAttributeMaxDynamicSharedMemorySize, 163840);

    wprep_all<<<2816, 256, 0, stream>>>(
        n1w1, i_n1w1, n1w2, i_n1w2, e1w1, i_p1r, i_p1s,
        n2w1, i_n2w1, n2w2, i_n2w2, e2w1, i_p2r, i_p2s, wB,
        e1w2, wA, e2w2, wC);

    node_fused<false><<<32, 256, 147456, stream>>>(
        x, nullptr, i_n1w1, n1b1, i_n1w2, n1b2, i_p1r, i_p1s, e1b1, P1);

    edge1_kernel<<<BE / 256, 512, 163840, stream>>>(
        P1, wA, e1b2, wB, G1, aggp0, aggp1);

    node_fused<true><<<32, 256, 147456, stream>>>(
        aggp0, aggp1, i_n2w1, n2b1, i_n2w2, n2b2, i_p2r, i_p2s, e2b1, P2);

    edge2_kernel<<<BE / 256, 512, 163840, stream>>>(
        G1, P2, wC, e2b2, ow, ob, out);
}

// Round 14
// 175.718 us; speedup vs baseline: 1.0301x; 1.0301x over previous
//
#include <hip/hip_runtime.h>
#include <hip/hip_bf16.h>

typedef unsigned short ushort_t;
typedef short bf16x8 __attribute__((ext_vector_type(8)));
typedef float f32x4 __attribute__((ext_vector_type(4)));

#define B_ 8
#define N_ 128
#define E_ 16256           // 128*127
#define BE 130048          // 8*E_

__device__ __forceinline__ float eluf(float x) {
    return x > 0.0f ? x : __expf(x) - 1.0f;
}
__device__ __forceinline__ ushort_t f2bf(float f) {
    union { float f; unsigned u; } v; v.f = f;
    return (ushort_t)((v.u + 0x7fffu + ((v.u >> 16) & 1u)) >> 16);
}
__device__ __forceinline__ float bf2f(ushort_t h) {
    union { unsigned u; float f; } v; v.u = ((unsigned)h) << 16;
    return v.f;
}

// async global->LDS, 16B per lane (node kernels only)
__device__ __forceinline__ void glds16(void* lds, const void* g) {
    __builtin_amdgcn_global_load_lds(
        (const __attribute__((address_space(1))) unsigned int*)g,
        (__attribute__((address_space(3))) unsigned int*)lds, 16, 0, 0);
}

// ---------------- weight image builders ----------------
// img32p (PLAIN, for register-loaded B): img[c*8192 + n*32 + kk] = w[c*32+kk][n]
__device__ __forceinline__ void img32p_elem(const float* __restrict__ w,
                                            ushort_t* __restrict__ img, int i) {
    int c = i >> 13;  int r = i & 8191;
    int n = r >> 5;   int kk = r & 31;
    img[i] = f2bf(w[(size_t)(c * 32 + kk) * 256 + n]);
}
// img128 (XOR-swizzled, for node glds path)
__device__ __forceinline__ void img128_elem(const float* __restrict__ w,
                                            ushort_t* __restrict__ img, int i) {
    int c = i >> 15;  int r = i & 32767;
    int n = r >> 7;   int wdx = r & 127;
    int up = wdx >> 3, j = wdx & 7;
    int u = up ^ (n & 15);
    int k = c * 128 + u * 8 + j;
    img[i] = f2bf(w[(size_t)k * 256 + n]);
}
__device__ __forceinline__ void img128_pad(const float* __restrict__ w,
                                           ushort_t* __restrict__ img, int i, int Kreal) {
    int c = i >> 15;  int r = i & 32767;
    int n = r >> 7;   int wdx = r & 127;
    int up = wdx >> 3, j = wdx & 7;
    int u = up ^ (n & 15);
    int k = c * 128 + u * 8 + j;
    img[i] = (k < Kreal) ? f2bf(w[(size_t)k * 256 + n]) : (ushort_t)0;
}

// 11 images x 65536 elems (node imgs img128; edge wA/wB/wC plain img32p)
__global__ __launch_bounds__(256) void wprep_all(
    const float* __restrict__ n1w1, ushort_t* __restrict__ s0,
    const float* __restrict__ n1w2, ushort_t* __restrict__ s1,
    const float* __restrict__ e1w1, ushort_t* __restrict__ s2, ushort_t* __restrict__ s3,
    const float* __restrict__ n2w1, ushort_t* __restrict__ s4,
    const float* __restrict__ n2w2, ushort_t* __restrict__ s5,
    const float* __restrict__ e2w1, ushort_t* __restrict__ s6, ushort_t* __restrict__ s7,
    ushort_t* __restrict__ s8,
    const float* __restrict__ e1w2, ushort_t* __restrict__ s9,
    const float* __restrict__ e2w2, ushort_t* __restrict__ s10)
{
    int gid = blockIdx.x * 256 + threadIdx.x;
    int img = gid >> 16, r = gid & 65535;
    switch (img) {
        case 0:  img128_pad (n1w1, s0, r, 196); break;
        case 1:  img128_elem(n1w2, s1, r); break;
        case 2:  img128_elem(e1w1, s2, r); break;
        case 3:  img128_elem(e1w1 + 65536, s3, r); break;
        case 4:  img128_elem(n2w1, s4, r); break;
        case 5:  img128_elem(n2w2, s5, r); break;
        case 6:  img128_elem(e2w1, s6, r); break;
        case 7:  img128_elem(e2w1 + 65536, s7, r); break;
        case 8:  img32p_elem(e2w1 + 131072, s8, r); break;   // W1x plain
        case 9:  img32p_elem(e1w2, s9, r); break;            // wA plain
        default: img32p_elem(e2w2, s10, r); break;           // wC plain
    }
}

// ---------------- fused node pipeline (unchanged from round 11/12) ----------------
template<bool TWOIN>
__global__ __launch_bounds__(256, 1) void node_fused(
    const float* __restrict__ in0, const float* __restrict__ in1,
    const ushort_t* __restrict__ iw1, const float* __restrict__ b1,
    const ushort_t* __restrict__ iw2, const float* __restrict__ b2,
    const ushort_t* __restrict__ ipr, const ushort_t* __restrict__ ips,
    const float* __restrict__ bE,
    float* __restrict__ P)
{
    extern __shared__ char smem[];
    const int t = threadIdx.x;
    const int wid = t >> 6, lane = t & 63, lr = lane & 15, lg = lane >> 4;
    const int r0 = blockIdx.x * 32;

    float bias1[4], bias2[4], biasP[4];
    #pragma unroll
    for (int f = 0; f < 4; ++f) {
        int col = wid * 64 + f * 16 + lr;
        bias1[f] = b1[col];
        bias2[f] = b2[col];
        biasP[f] = 0.5f * bE[col];
    }

    f32x4 acc[2][4];
    #pragma unroll
    for (int m = 0; m < 2; ++m)
        #pragma unroll
        for (int f = 0; f < 4; ++f) acc[m][f] = f32x4{0.f, 0.f, 0.f, 0.f};

    auto stageW = [&](const ushort_t* img, int c, int p) {
        const char* src = (const char*)img + (size_t)c * 65536 + wid * 16384 + lane * 16;
        char* dst = smem + 16384 + p * 65536 + wid * 16384;
        #pragma unroll
        for (int it = 0; it < 16; ++it) glds16(dst + it * 1024, src + it * 1024);
    };

    int cc = 0;
    auto runGemm = [&](const ushort_t* img, const ushort_t* nimg) {
        for (int c = 0; c < 2; ++c) {
            const int p = cc & 1;
            if (c + 1 < 2)  stageW(img, 1, p ^ 1);
            else if (nimg)  stageW(nimg, 0, p ^ 1);
            const char* Wp = smem + 16384 + p * 65536;
            #pragma unroll
            for (int ks = 0; ks < 4; ++ks) {
                const int c32 = c * 4 + ks;
                bf16x8 a[2], b[4];
                const int qh = ((c32 * 4 + lg) ^ (lr & 7)) << 4;
                #pragma unroll
                for (int m = 0; m < 2; ++m)
                    a[m] = *(const bf16x8*)(smem + (m * 16 + lr) * 512 + qh);
                #pragma unroll
                for (int f = 0; f < 4; ++f)
                    b[f] = *(const bf16x8*)(Wp + (wid * 64 + f * 16 + lr) * 256 + (((ks * 4 + lg) ^ lr) << 4));
                #pragma unroll
                for (int m = 0; m < 2; ++m)
                    #pragma unroll
                    for (int f = 0; f < 4; ++f)
                        acc[m][f] = __builtin_amdgcn_mfma_f32_16x16x32_bf16(a[m], b[f], acc[m][f], 0, 0, 0);
            }
            __syncthreads();
            ++cc;
        }
    };

    auto transition = [&](const float* bv) {
        #pragma unroll
        for (int m = 0; m < 2; ++m)
            #pragma unroll
            for (int f = 0; f < 4; ++f) {
                const int col = wid * 64 + f * 16 + lr;
                const int ch = col >> 3;
                #pragma unroll
                for (int r = 0; r < 4; ++r) {
                    const int row = m * 16 + lg * 4 + r;
                    float v = eluf(acc[m][f][r] + bv[f]);
                    *(ushort_t*)(smem + row * 512 + ((ch ^ (row & 7)) << 4) + ((col & 7) << 1)) = f2bf(v);
                }
                acc[m][f] = f32x4{0.f, 0.f, 0.f, 0.f};
            }
        __syncthreads();
    };

    auto pwrite = [&](int half) {
        #pragma unroll
        for (int m = 0; m < 2; ++m)
            #pragma unroll
            for (int f = 0; f < 4; ++f) {
                const int col = wid * 64 + f * 16 + lr;
                #pragma unroll
                for (int r = 0; r < 4; ++r) {
                    const int row = m * 16 + lg * 4 + r;
                    P[(size_t)(r0 + row) * 512 + half * 256 + col] = acc[m][f][r] + biasP[f];
                }
                acc[m][f] = f32x4{0.f, 0.f, 0.f, 0.f};
            }
    };

    stageW(iw1, 0, 0);
    for (int idx = t; idx < 32 * 128; idx += 256) {
        const int row = idx >> 7;
        const int c0 = (idx & 127) * 2;
        float v0, v1;
        if (TWOIN) {
            const float* pa = in0 + (size_t)(r0 + row) * 256;
            const float* pb = in1 + (size_t)(r0 + row) * 256;
            v0 = pa[c0] + pb[c0];
            v1 = pa[c0 + 1] + pb[c0 + 1];
        } else {
            const float* pa = in0 + (size_t)(r0 + row) * 196;
            v0 = (c0 < 196) ? pa[c0] : 0.f;
            v1 = (c0 + 1 < 196) ? pa[c0 + 1] : 0.f;
        }
        unsigned u = (unsigned)f2bf(v0) | ((unsigned)f2bf(v1) << 16);
        const int ch = c0 >> 3;
        *(unsigned*)(smem + row * 512 + ((ch ^ (row & 7)) << 4) + (c0 & 7) * 2) = u;
    }
    __syncthreads();

    runGemm(iw1, iw2);
    transition(bias1);
    runGemm(iw2, ipr);
    transition(bias2);
    runGemm(ipr, ips);
    pwrite(0);
    runGemm(ips, nullptr);
    pwrite(1);
}

// ---------------- edge1': build -> regGEMM(wA) -> {e1 + partials} -> regGEMM(wB) -> G1 ----------------
// LDS: A-tile 256x512B XOR [0,128K), pt [128K,136K). B streamed to REGISTERS (no W LDS, no K-loop barriers).
__global__ __launch_bounds__(512, 2) void edge1_kernel(
    const float* __restrict__ P1,
    const ushort_t* __restrict__ wAimg, const float* __restrict__ biasA,   // e1b2
    const ushort_t* __restrict__ wBimg,                                    // W1x plain
    ushort_t* __restrict__ G1,
    float* __restrict__ aggp0, float* __restrict__ aggp1)
{
    extern __shared__ char smem[];
    const int t = threadIdx.x;
    const int wid = t >> 6, lane = t & 63, lr = lane & 15, lg = lane >> 4;
    const int wr = wid >> 1, wc = wid & 1;
    const int blockRow = blockIdx.x * 256;
    const int boff = (wc * 128 + lr) * 32 + lg * 8;   // per-lane element offset within chunk

    float bA[8];
    #pragma unroll
    for (int f = 0; f < 8; ++f) bA[f] = biasA[wc * 128 + f * 16 + lr];

    f32x4 acc[4][8];
    #pragma unroll
    for (int m = 0; m < 4; ++m)
        #pragma unroll
        for (int f = 0; f < 8; ++f) acc[m][f] = f32x4{0.f, 0.f, 0.f, 0.f};

    // register-B GEMM: 8 chunks BK=32, 2-deep register ring, NO barriers
    auto gemmReg = [&](const ushort_t* wimg) {
        const ushort_t* wb = wimg + boff;
        bf16x8 brg[2][8];
        #pragma unroll
        for (int f = 0; f < 8; ++f) brg[0][f] = *(const bf16x8*)(wb + 0 * 8192 + f * 512);
        #pragma unroll
        for (int f = 0; f < 8; ++f) brg[1][f] = *(const bf16x8*)(wb + 1 * 8192 + f * 512);
        #pragma unroll
        for (int c = 0; c < 8; ++c) {
            bf16x8 a[4];
            const int qh = ((c * 4 + lg) ^ (lr & 7)) << 4;
            #pragma unroll
            for (int m = 0; m < 4; ++m)
                a[m] = *(const bf16x8*)(smem + (wr * 64 + m * 16 + lr) * 512 + qh);
            #pragma unroll
            for (int m = 0; m < 4; ++m)
                #pragma unroll
                for (int f = 0; f < 8; ++f)
                    acc[m][f] = __builtin_amdgcn_mfma_f32_16x16x32_bf16(a[m], brg[c & 1][f], acc[m][f], 0, 0, 0);
            if (c + 2 < 8) {
                #pragma unroll
                for (int f = 0; f < 8; ++f)
                    brg[c & 1][f] = *(const bf16x8*)(wb + (size_t)(c + 2) * 8192 + f * 512);
            }
        }
    };

    // ---- build A = elu(P1r + P1s): coalesced, XOR LDS layout ----
    #pragma unroll 4
    for (int j = 0; j < 32; ++j) {
        const int row = wid * 32 + j;
        const int rg = blockRow + row;
        const int b = rg / E_; const int e = rg - b * E_;
        const int rcv = e / 127; const int kk = e - rcv * 127;
        const int snd = kk + (kk >= rcv ? 1 : 0);
        const float4 vr = *(const float4*)(P1 + (size_t)(b * N_ + rcv) * 512 + lane * 4);
        const float4 vs = *(const float4*)(P1 + (size_t)(b * N_ + snd) * 512 + 256 + lane * 4);
        unsigned u0 = (unsigned)f2bf(eluf(vr.x + vs.x)) | ((unsigned)f2bf(eluf(vr.y + vs.y)) << 16);
        unsigned u1 = (unsigned)f2bf(eluf(vr.z + vs.z)) | ((unsigned)f2bf(eluf(vr.w + vs.w)) << 16);
        const int byte = row * 512 + ((((lane >> 1) ^ (row & 7))) << 4) + (lane & 1) * 8;
        *(uint2*)(smem + byte) = make_uint2(u0, u1);
    }
    __syncthreads();                     // A published

    gemmReg(wAimg);                      // GEMM A: hid1 @ wA, barrier-free
    __syncthreads();                     // all A reads done before in-place rewrite

    // ---- transition: e1 = elu(acc + bA) -> A-tile (XOR) + segment partials ----
    const int gR0 = blockRow + wr * 64;
    const int sFirst = gR0 / 127;
    const int bk = 127 - (gR0 - sFirst * 127);
    float s0[8], s1[8];
    #pragma unroll
    for (int f = 0; f < 8; ++f) { s0[f] = 0.f; s1[f] = 0.f; }
    #pragma unroll
    for (int m = 0; m < 4; ++m)
        #pragma unroll
        for (int f = 0; f < 8; ++f) {
            const int col = wc * 128 + f * 16 + lr;
            const int ch = col >> 3;
            #pragma unroll
            for (int r = 0; r < 4; ++r) {
                const int rowL = m * 16 + lg * 4 + r;
                const int row = wr * 64 + rowL;
                float v = eluf(acc[m][f][r] + bA[f]);
                *(ushort_t*)(smem + row * 512 + ((ch ^ (row & 7)) << 4) + ((col & 7) << 1)) = f2bf(v);
                if (rowL < bk) s0[f] += v; else s1[f] += v;
            }
            acc[m][f] = f32x4{0.f, 0.f, 0.f, 0.f};
        }
    #pragma unroll
    for (int f = 0; f < 8; ++f) {
        s0[f] += __shfl_xor(s0[f], 16); s0[f] += __shfl_xor(s0[f], 32);
        s1[f] += __shfl_xor(s1[f], 16); s1[f] += __shfl_xor(s1[f], 32);
    }
    float* pt = (float*)(smem + 131072);   // dedicated 8KB
    if (lg == 0) {
        #pragma unroll
        for (int f = 0; f < 8; ++f) {
            pt[(wid * 2 + 0) * 128 + f * 16 + lr] = s0[f];
            pt[(wid * 2 + 1) * 128 + f * 16 + lr] = s1[f];
        }
    }
    __syncthreads();                     // new A + pt published
    {
        const int S0 = blockRow / 127;
        const int last = (blockRow + 255) / 127;
        const int cnt = last - S0 + 1;
        for (int task = t; task < cnt * 256; task += 512) {
            const int k = task >> 8;
            const int col = task & 255;
            const int sigma = S0 + k;
            const int wcq = col >> 7, c128 = col & 127;
            float sum = 0.f;
            #pragma unroll
            for (int w2r = 0; w2r < 4; ++w2r) {
                int sf = (blockRow + w2r * 64) / 127;
                int jj = sigma - sf;
                if (jj == 0 || jj == 1)
                    sum += pt[((w2r * 2 + wcq) * 2 + jj) * 128 + c128];
            }
            const bool startIn = (127 * sigma >= blockRow);
            const bool endIn = (127 * sigma + 127 <= blockRow + 256);
            if (startIn) {
                aggp0[(size_t)sigma * 256 + col] = sum;
                if (endIn) aggp1[(size_t)sigma * 256 + col] = 0.f;
            } else {
                aggp1[(size_t)sigma * 256 + col] = sum;
            }
        }
    }

    gemmReg(wBimg);                      // GEMM B: e1 @ W1x, barrier-free
    __syncthreads();                     // all A reads done before slice overwrite

    // ---- epilogue: G1 = acc (raw bf16) via wave-private slice -> coalesced stores ----
    char* slice = smem + wid * 16384;
    #pragma unroll
    for (int m = 0; m < 4; ++m)
        #pragma unroll
        for (int f = 0; f < 8; ++f) {
            const int col = f * 16 + lr;
            const int cch = col >> 3;
            #pragma unroll
            for (int r = 0; r < 4; ++r) {
                const int rowL = m * 16 + lg * 4 + r;
                *(ushort_t*)(slice + rowL * 256 + ((cch ^ (rowL & 7)) << 4) + ((col & 7) << 1)) =
                    f2bf(acc[m][f][r]);
            }
        }
    asm volatile("s_waitcnt lgkmcnt(0)" ::: "memory");
    #pragma unroll
    for (int it = 0; it < 16; ++it) {
        const int q = it * 64 + lane;
        const int row = q >> 4, ccp = q & 15;
        bf16x8 v = *(const bf16x8*)(slice + row * 256 + (ccp << 4));
        const int cch = ccp ^ (row & 7);
        const int grow = blockRow + wr * 64 + row;
        *(bf16x8*)(G1 + (size_t)grow * 256 + wc * 128 + cch * 8) = v;
    }
}

// ---------------- edge2': build hid2 = elu(G1 + P2r + P2s) -> regGEMM(wC) -> project ----------------
// LDS: A-tile 256x512B XOR [0,128K). B in registers, no K-loop barriers.
__global__ __launch_bounds__(512, 2) void edge2_kernel(
    const ushort_t* __restrict__ G1, const float* __restrict__ P2,
    const ushort_t* __restrict__ wCimg, const float* __restrict__ bC,
    const float* __restrict__ ow, const float* __restrict__ ob,
    float* __restrict__ out)
{
    extern __shared__ char smem[];
    const int t = threadIdx.x;
    const int wid = t >> 6, lane = t & 63, lr = lane & 15, lg = lane >> 4;
    const int wr = wid >> 1, wc = wid & 1;
    const int blockRow = blockIdx.x * 256;
    const int boff = (wc * 128 + lr) * 32 + lg * 8;

    float biasC[8];
    #pragma unroll
    for (int f = 0; f < 8; ++f) biasC[f] = bC[wc * 128 + f * 16 + lr];

    f32x4 acc[4][8];
    #pragma unroll
    for (int m = 0; m < 4; ++m)
        #pragma unroll
        for (int f = 0; f < 8; ++f) acc[m][f] = f32x4{0.f, 0.f, 0.f, 0.f};

    // ---- build: hid2 = elu(G1 + P2r + P2s), coalesced, XOR LDS layout ----
    #pragma unroll 4
    for (int j = 0; j < 32; ++j) {
        const int row = wid * 32 + j;
        const int rg = blockRow + row;
        const int b = rg / E_; const int e = rg - b * E_;
        const int rcv = e / 127; const int kk = e - rcv * 127;
        const int snd = kk + (kk >= rcv ? 1 : 0);
        const ushort4 g4 = *(const ushort4*)(G1 + (size_t)rg * 256 + lane * 4);
        const float4 vr = *(const float4*)(P2 + (size_t)(b * N_ + rcv) * 512 + lane * 4);
        const float4 vs = *(const float4*)(P2 + (size_t)(b * N_ + snd) * 512 + 256 + lane * 4);
        unsigned u0 = (unsigned)f2bf(eluf(bf2f(g4.x) + vr.x + vs.x))
                    | ((unsigned)f2bf(eluf(bf2f(g4.y) + vr.y + vs.y)) << 16);
        unsigned u1 = (unsigned)f2bf(eluf(bf2f(g4.z) + vr.z + vs.z))
                    | ((unsigned)f2bf(eluf(bf2f(g4.w) + vr.w + vs.w)) << 16);
        const int byte = row * 512 + ((((lane >> 1) ^ (row & 7))) << 4) + (lane & 1) * 8;
        *(uint2*)(smem + byte) = make_uint2(u0, u1);
    }
    __syncthreads();

    // ---- GEMM: hid2 @ W2e2, register-B, barrier-free ----
    {
        const ushort_t* wb = wCimg + boff;
        bf16x8 brg[2][8];
        #pragma unroll
        for (int f = 0; f < 8; ++f) brg[0][f] = *(const bf16x8*)(wb + 0 * 8192 + f * 512);
        #pragma unroll
        for (int f = 0; f < 8; ++f) brg[1][f] = *(const bf16x8*)(wb + 1 * 8192 + f * 512);
        #pragma unroll
        for (int c = 0; c < 8; ++c) {
            bf16x8 a[4];
            const int qh = ((c * 4 + lg) ^ (lr & 7)) << 4;
            #pragma unroll
            for (int m = 0; m < 4; ++m)
                a[m] = *(const bf16x8*)(smem + (wr * 64 + m * 16 + lr) * 512 + qh);
            #pragma unroll
            for (int m = 0; m < 4; ++m)
                #pragma unroll
                for (int f = 0; f < 8; ++f)
                    acc[m][f] = __builtin_amdgcn_mfma_f32_16x16x32_bf16(a[m], brg[c & 1][f], acc[m][f], 0, 0, 0);
            if (c + 2 < 8) {
                #pragma unroll
                for (int f = 0; f < 8; ++f)
                    brg[c & 1][f] = *(const bf16x8*)(wb + (size_t)(c + 2) * 8192 + f * 512);
            }
        }
    }
    __syncthreads();                     // A reads done before part[] overwrite

    // ---- epilogue: fused projection to [row][2] ----
    float ow0[8], ow1[8];
    #pragma unroll
    for (int f = 0; f < 8; ++f) {
        int col = wc * 128 + f * 16 + lr;
        ow0[f] = ow[col * 2 + 0];
        ow1[f] = ow[col * 2 + 1];
    }
    float s0[4][4], s1[4][4];
    #pragma unroll
    for (int m = 0; m < 4; ++m)
        #pragma unroll
        for (int r = 0; r < 4; ++r) { s0[m][r] = 0.f; s1[m][r] = 0.f; }
    #pragma unroll
    for (int m = 0; m < 4; ++m)
        #pragma unroll
        for (int f = 0; f < 8; ++f)
            #pragma unroll
            for (int r = 0; r < 4; ++r) {
                float v = eluf(acc[m][f][r] + biasC[f]);
                s0[m][r] = fmaf(v, ow0[f], s0[m][r]);
                s1[m][r] = fmaf(v, ow1[f], s1[m][r]);
            }
    #pragma unroll
    for (int msk = 1; msk <= 8; msk <<= 1)
        #pragma unroll
        for (int m = 0; m < 4; ++m)
            #pragma unroll
            for (int r = 0; r < 4; ++r) {
                s0[m][r] += __shfl_xor(s0[m][r], msk);
                s1[m][r] += __shfl_xor(s1[m][r], msk);
            }
    float* part = (float*)smem;
    if (lr == 0) {
        #pragma unroll
        for (int m = 0; m < 4; ++m)
            #pragma unroll
            for (int r = 0; r < 4; ++r) {
                const int row = wr * 64 + m * 16 + lg * 4 + r;
                part[(row * 2 + 0) * 2 + wc] = s0[m][r];
                part[(row * 2 + 1) * 2 + wc] = s1[m][r];
            }
    }
    __syncthreads();
    const int row = t >> 1, chn = t & 1;
    float val = part[(row * 2 + chn) * 2 + 0] + part[(row * 2 + chn) * 2 + 1] + ob[chn];
    out[(size_t)(blockRow + row) * 2 + chn] = val;
}

extern "C" void kernel_launch(void* const* d_in, const int* in_sizes, int n_in,
                              void* d_out, int out_size, void* d_ws, size_t ws_size,
                              hipStream_t stream)
{
    const float* x    = (const float*)d_in[0];
    const float* n1w1 = (const float*)d_in[3];
    const float* n1b1 = (const float*)d_in[4];
    const float* n1w2 = (const float*)d_in[5];
    const float* n1b2 = (const float*)d_in[6];
    const float* e1w1 = (const float*)d_in[7];
    const float* e1b1 = (const float*)d_in[8];
    const float* e1w2 = (const float*)d_in[9];
    const float* e1b2 = (const float*)d_in[10];
    const float* n2w1 = (const float*)d_in[11];
    const float* n2b1 = (const float*)d_in[12];
    const float* n2w2 = (const float*)d_in[13];
    const float* n2b2 = (const float*)d_in[14];
    const float* e2w1 = (const float*)d_in[15];
    const float* e2b1 = (const float*)d_in[16];
    const float* e2w2 = (const float*)d_in[17];
    const float* e2b2 = (const float*)d_in[18];
    const float* ow   = (const float*)d_in[19];
    const float* ob   = (const float*)d_in[20];

    char* ws = (char*)d_ws;
    const size_t KB = 1024;
    ushort_t* i_n1w1 = (ushort_t*)(ws + 0 * 128 * KB);
    ushort_t* i_n1w2 = (ushort_t*)(ws + 1 * 128 * KB);
    ushort_t* i_p1r  = (ushort_t*)(ws + 2 * 128 * KB);
    ushort_t* i_p1s  = (ushort_t*)(ws + 3 * 128 * KB);
    ushort_t* i_n2w1 = (ushort_t*)(ws + 4 * 128 * KB);
    ushort_t* i_n2w2 = (ushort_t*)(ws + 5 * 128 * KB);
    ushort_t* i_p2r  = (ushort_t*)(ws + 6 * 128 * KB);
    ushort_t* i_p2s  = (ushort_t*)(ws + 7 * 128 * KB);
    ushort_t* wB     = (ushort_t*)(ws + 8 * 128 * KB);
    ushort_t* wA     = (ushort_t*)(ws + 9 * 128 * KB);
    ushort_t* wC     = (ushort_t*)(ws + 10 * 128 * KB);
    float*    P1    = (float*)(ws + 1536 * KB);            // 2MB [1024][512]
    float*    P2    = (float*)(ws + 1536 * KB + (2u << 20));
    float*    aggp0 = (float*)(ws + 1536 * KB + (4u << 20));
    float*    aggp1 = (float*)(ws + 1536 * KB + (5u << 20));
    ushort_t* G1    = (ushort_t*)(ws + 1536 * KB + (6u << 20)); // 66.6MB [BE][256] bf16

    float* out = (float*)d_out;

    hipFuncSetAttribute((const void*)node_fused<false>,
                        hipFuncAttributeMaxDynamicSharedMemorySize, 147456);
    hipFuncSetAttribute((const void*)node_fused<true>,
                        hipFuncAttributeMaxDynamicSharedMemorySize, 147456);
    hipFuncSetAttribute((const void*)edge1_kernel,
                        hipFuncAttributeMaxDynamicSharedMemorySize, 139264);
    hipFuncSetAttribute((const void*)edge2_kernel,
                        hipFuncAttributeMaxDynamicSharedMemorySize, 131072);

    wprep_all<<<2816, 256, 0, stream>>>(
        n1w1, i_n1w1, n1w2, i_n1w2, e1w1, i_p1r, i_p1s,
        n2w1, i_n2w1, n2w2, i_n2w2, e2w1, i_p2r, i_p2s, wB,
        e1w2, wA, e2w2, wC);

    node_fused<false><<<32, 256, 147456, stream>>>(
        x, nullptr, i_n1w1, n1b1, i_n1w2, n1b2, i_p1r, i_p1s, e1b1, P1);

    edge1_kernel<<<BE / 256, 512, 139264, stream>>>(
        P1, wA, e1b2, wB, G1, aggp0, aggp1);

    node_fused<true><<<32, 256, 147456, stream>>>(
        aggp0, aggp1, i_n2w1, n2b1, i_n2w2, n2b2, i_p2r, i_p2s, e2b1, P2);

    edge2_kernel<<<BE / 256, 512, 131072, stream>>>(
        G1, P2, wC, e2b2, ow, ob, out);
}

// Round 15
// 160.562 us; speedup vs baseline: 1.1274x; 1.0944x over previous
//
#include <hip/hip_runtime.h>
#include <hip/hip_bf16.h>

typedef unsigned short ushort_t;
typedef short bf16x8 __attribute__((ext_vector_type(8)));
typedef float f32x4 __attribute__((ext_vector_type(4)));

#define B_ 8
#define N_ 128
#define E_ 16256           // 128*127
#define BE 130048          // 8*E_

__device__ __forceinline__ float eluf(float x) {
    return x > 0.0f ? x : __expf(x) - 1.0f;
}
__device__ __forceinline__ ushort_t f2bf(float f) {
    union { float f; unsigned u; } v; v.f = f;
    return (ushort_t)((v.u + 0x7fffu + ((v.u >> 16) & 1u)) >> 16);
}
__device__ __forceinline__ float bf2f(ushort_t h) {
    union { unsigned u; float f; } v; v.u = ((unsigned)h) << 16;
    return v.f;
}

// async global->LDS, 16B per lane; LDS dest = wave-uniform base + lane*16.
__device__ __forceinline__ void glds16(void* lds, const void* g) {
    __builtin_amdgcn_global_load_lds(
        (const __attribute__((address_space(1))) unsigned int*)g,
        (__attribute__((address_space(3))) unsigned int*)lds, 16, 0, 0);
}

// ---------------- weight image builders ----------------
// img32: chunk c (32k x 256n = 16KB): img[c][n][q'][j] = w[c*32 + (q'^((n>>1)&3))*8 + j][n]
__device__ __forceinline__ void img32_elem(const float* __restrict__ w,
                                           ushort_t* __restrict__ img, int i) {
    int c = i >> 13;  int r = i & 8191;
    int n = r >> 5;   int jq = r & 31;
    int quad = jq >> 3, j = jq & 7;
    int kc = quad ^ ((n >> 1) & 3);
    int k = c * 32 + kc * 8 + j;
    img[i] = f2bf(w[(size_t)k * 256 + n]);
}
// img64: chunk c (64k x 256n = 32KB): img[c][n][u'][j] = w[c*64 + (u'^(n&7))*8 + j][n]
__device__ __forceinline__ void img64_elem(const float* __restrict__ w,
                                           ushort_t* __restrict__ img, int i) {
    int c = i >> 14;  int r = i & 16383;
    int n = r >> 6;   int wdx = r & 63;
    int up = wdx >> 3, j = wdx & 7;
    int u = up ^ (n & 7);
    int k = c * 64 + u * 8 + j;
    img[i] = f2bf(w[(size_t)k * 256 + n]);
}
// img128: chunk c (128k x 256n = 64KB): img[c][n][u'][j] = w[c*128 + (u'^(n&15))*8 + j][n]
__device__ __forceinline__ void img128_elem(const float* __restrict__ w,
                                            ushort_t* __restrict__ img, int i) {
    int c = i >> 15;  int r = i & 32767;
    int n = r >> 7;   int wdx = r & 127;
    int up = wdx >> 3, j = wdx & 7;
    int u = up ^ (n & 15);
    int k = c * 128 + u * 8 + j;
    img[i] = f2bf(w[(size_t)k * 256 + n]);
}
// img128 with K zero-padding
__device__ __forceinline__ void img128_pad(const float* __restrict__ w,
                                           ushort_t* __restrict__ img, int i, int Kreal) {
    int c = i >> 15;  int r = i & 32767;
    int n = r >> 7;   int wdx = r & 127;
    int up = wdx >> 3, j = wdx & 7;
    int u = up ^ (n & 15);
    int k = c * 128 + u * 8 + j;
    img[i] = (k < Kreal) ? f2bf(w[(size_t)k * 256 + n]) : (ushort_t)0;
}

// 11 images x 65536 elems (node imgs img128; edge wA/wC img32, wB img64)
__global__ __launch_bounds__(256) void wprep_all(
    const float* __restrict__ n1w1, ushort_t* __restrict__ s0,
    const float* __restrict__ n1w2, ushort_t* __restrict__ s1,
    const float* __restrict__ e1w1, ushort_t* __restrict__ s2, ushort_t* __restrict__ s3,
    const float* __restrict__ n2w1, ushort_t* __restrict__ s4,
    const float* __restrict__ n2w2, ushort_t* __restrict__ s5,
    const float* __restrict__ e2w1, ushort_t* __restrict__ s6, ushort_t* __restrict__ s7,
    ushort_t* __restrict__ s8,
    const float* __restrict__ e1w2, ushort_t* __restrict__ s9,
    const float* __restrict__ e2w2, ushort_t* __restrict__ s10)
{
    int gid = blockIdx.x * 256 + threadIdx.x;
    int img = gid >> 16, r = gid & 65535;
    switch (img) {
        case 0:  img128_pad (n1w1, s0, r, 196); break;
        case 1:  img128_elem(n1w2, s1, r); break;
        case 2:  img128_elem(e1w1, s2, r); break;
        case 3:  img128_elem(e1w1 + 65536, s3, r); break;
        case 4:  img128_elem(n2w1, s4, r); break;
        case 5:  img128_elem(n2w2, s5, r); break;
        case 6:  img128_elem(e2w1, s6, r); break;
        case 7:  img128_elem(e2w1 + 65536, s7, r); break;
        case 8:  img64_elem (e2w1 + 131072, s8, r); break;   // W1x img64
        case 9:  img32_elem (e1w2, s9, r); break;            // wA img32
        default: img32_elem (e2w2, s10, r); break;           // wC img32
    }
}

// ---------------- fused node pipeline (MFMA): in -> h1 -> h -> P[1024][512] ----------------
// 32 blocks x 32 rows, 4 waves. LDS: A 32x512B XOR [0,16K), W ring 2x64K [16K,144K).
// 4 chained BK=128 GEMM stages (2 chunks each)
template<bool TWOIN>
__global__ __launch_bounds__(256, 1) void node_fused(
    const float* __restrict__ in0, const float* __restrict__ in1,
    const ushort_t* __restrict__ iw1, const float* __restrict__ b1,
    const ushort_t* __restrict__ iw2, const float* __restrict__ b2,
    const ushort_t* __restrict__ ipr, const ushort_t* __restrict__ ips,
    const float* __restrict__ bE,
    float* __restrict__ P)
{
    extern __shared__ char smem[];
    const int t = threadIdx.x;
    const int wid = t >> 6, lane = t & 63, lr = lane & 15, lg = lane >> 4;
    const int r0 = blockIdx.x * 32;

    float bias1[4], bias2[4], biasP[4];
    #pragma unroll
    for (int f = 0; f < 4; ++f) {
        int col = wid * 64 + f * 16 + lr;
        bias1[f] = b1[col];
        bias2[f] = b2[col];
        biasP[f] = 0.5f * bE[col];
    }

    f32x4 acc[2][4];
    #pragma unroll
    for (int m = 0; m < 2; ++m)
        #pragma unroll
        for (int f = 0; f < 4; ++f) acc[m][f] = f32x4{0.f, 0.f, 0.f, 0.f};

    // stage one 64KB img128 chunk into ring slot p (16 glds/thread, linear copy)
    auto stageW = [&](const ushort_t* img, int c, int p) {
        const char* src = (const char*)img + (size_t)c * 65536 + wid * 16384 + lane * 16;
        char* dst = smem + 16384 + p * 65536 + wid * 16384;
        #pragma unroll
        for (int it = 0; it < 16; ++it) glds16(dst + it * 1024, src + it * 1024);
    };

    int cc = 0;   // global chunk counter -> ring parity
    auto runGemm = [&](const ushort_t* img, const ushort_t* nimg) {
        for (int c = 0; c < 2; ++c) {
            const int p = cc & 1;
            if (c + 1 < 2)  stageW(img, 1, p ^ 1);
            else if (nimg)  stageW(nimg, 0, p ^ 1);
            const char* Wp = smem + 16384 + p * 65536;
            #pragma unroll
            for (int ks = 0; ks < 4; ++ks) {
                const int c32 = c * 4 + ks;           // 32k-chunk index within stage (0..7)
                bf16x8 a[2], b[4];
                const int qh = ((c32 * 4 + lg) ^ (lr & 7)) << 4;
                #pragma unroll
                for (int m = 0; m < 2; ++m)
                    a[m] = *(const bf16x8*)(smem + (m * 16 + lr) * 512 + qh);
                #pragma unroll
                for (int f = 0; f < 4; ++f)
                    b[f] = *(const bf16x8*)(Wp + (wid * 64 + f * 16 + lr) * 256 + (((ks * 4 + lg) ^ lr) << 4));
                #pragma unroll
                for (int m = 0; m < 2; ++m)
                    #pragma unroll
                    for (int f = 0; f < 4; ++f)
                        acc[m][f] = __builtin_amdgcn_mfma_f32_16x16x32_bf16(a[m], b[f], acc[m][f], 0, 0, 0);
            }
            __syncthreads();
            ++cc;
        }
    };

    auto transition = [&](const float* bv) {   // acc -> elu(acc+b) -> A tile, reset acc
        #pragma unroll
        for (int m = 0; m < 2; ++m)
            #pragma unroll
            for (int f = 0; f < 4; ++f) {
                const int col = wid * 64 + f * 16 + lr;
                const int ch = col >> 3;
                #pragma unroll
                for (int r = 0; r < 4; ++r) {
                    const int row = m * 16 + lg * 4 + r;
                    float v = eluf(acc[m][f][r] + bv[f]);
                    *(ushort_t*)(smem + row * 512 + ((ch ^ (row & 7)) << 4) + ((col & 7) << 1)) = f2bf(v);
                }
                acc[m][f] = f32x4{0.f, 0.f, 0.f, 0.f};
            }
        __syncthreads();
    };

    auto pwrite = [&](int half) {              // acc + 0.5bE -> P[:, half*256+col], reset acc
        #pragma unroll
        for (int m = 0; m < 2; ++m)
            #pragma unroll
            for (int f = 0; f < 4; ++f) {
                const int col = wid * 64 + f * 16 + lr;
                #pragma unroll
                for (int r = 0; r < 4; ++r) {
                    const int row = m * 16 + lg * 4 + r;
                    P[(size_t)(r0 + row) * 512 + half * 256 + col] = acc[m][f][r] + biasP[f];
                }
                acc[m][f] = f32x4{0.f, 0.f, 0.f, 0.f};
            }
    };

    // ---- prologue: prefetch w1 chunk 0 + VALU-stage A0 (f32 -> bf16, XOR, zero-pad) ----
    stageW(iw1, 0, 0);
    for (int idx = t; idx < 32 * 128; idx += 256) {
        const int row = idx >> 7;
        const int c0 = (idx & 127) * 2;
        float v0, v1;
        if (TWOIN) {
            const float* pa = in0 + (size_t)(r0 + row) * 256;
            const float* pb = in1 + (size_t)(r0 + row) * 256;
            v0 = pa[c0] + pb[c0];
            v1 = pa[c0 + 1] + pb[c0 + 1];
        } else {
            const float* pa = in0 + (size_t)(r0 + row) * 196;
            v0 = (c0 < 196) ? pa[c0] : 0.f;
            v1 = (c0 + 1 < 196) ? pa[c0 + 1] : 0.f;
        }
        unsigned u = (unsigned)f2bf(v0) | ((unsigned)f2bf(v1) << 16);
        const int ch = c0 >> 3;
        *(unsigned*)(smem + row * 512 + ((ch ^ (row & 7)) << 4) + (c0 & 7) * 2) = u;
    }
    __syncthreads();

    runGemm(iw1, iw2);     // layer 1 (K padded to 256)
    transition(bias1);
    runGemm(iw2, ipr);     // layer 2
    transition(bias2);
    runGemm(ipr, ips);     // P r-half
    pwrite(0);
    runGemm(ips, nullptr); // P s-half
    pwrite(1);
}

// ---------------- edge1: A=elu(P1r+P1s) built in LDS -> GEMM wA -> e1 + partials ----------------
// LDS: A-tile 256x512B XOR layout [0,128K), wA ring 2x16K [128K,160K)
__global__ __launch_bounds__(512, 2) void edge1_kernel(
    const float* __restrict__ P1,
    const ushort_t* __restrict__ wimg, const float* __restrict__ bias,   // e1b2
    ushort_t* __restrict__ eout,
    float* __restrict__ aggp0, float* __restrict__ aggp1)
{
    extern __shared__ char smem[];
    const int t = threadIdx.x;
    const int wid = t >> 6, lane = t & 63, lr = lane & 15, lg = lane >> 4;
    const int wr = wid >> 1, wc = wid & 1;
    const int q4 = (lg ^ ((lr >> 1) & 3)) << 4;
    const int blockRow = blockIdx.x * 256;

    auto stageW = [&](int c, int p) {
        const char* src = (const char*)wimg + (size_t)c * 16384 + wid * 2048 + lane * 16;
        char* dst = smem + 131072 + p * 16384 + wid * 2048;
        glds16(dst, src);
        glds16(dst + 1024, src + 1024);
    };

    float biasA[8];
    #pragma unroll
    for (int f = 0; f < 8; ++f) biasA[f] = bias[wc * 128 + f * 16 + lr];

    f32x4 acc[4][8];
    #pragma unroll
    for (int m = 0; m < 4; ++m)
        #pragma unroll
        for (int f = 0; f < 8; ++f) acc[m][f] = f32x4{0.f, 0.f, 0.f, 0.f};

    stageW(0, 0);
    // ---- build A: wave handles rows [wid*32, wid*32+32); lane covers cols lane*4..+3 ----
    #pragma unroll 4
    for (int j = 0; j < 32; ++j) {
        const int row = wid * 32 + j;
        const int rg = blockRow + row;
        const int b = rg / E_; const int e = rg - b * E_;
        const int rcv = e / 127; const int kk = e - rcv * 127;
        const int snd = kk + (kk >= rcv ? 1 : 0);
        const float4 vr = *(const float4*)(P1 + (size_t)(b * N_ + rcv) * 512 + lane * 4);
        const float4 vs = *(const float4*)(P1 + (size_t)(b * N_ + snd) * 512 + 256 + lane * 4);
        unsigned u0 = (unsigned)f2bf(eluf(vr.x + vs.x)) | ((unsigned)f2bf(eluf(vr.y + vs.y)) << 16);
        unsigned u1 = (unsigned)f2bf(eluf(vr.z + vs.z)) | ((unsigned)f2bf(eluf(vr.w + vs.w)) << 16);
        const int byte = row * 512 + ((((lane >> 1) ^ (row & 7))) << 4) + (lane & 1) * 8;
        *(uint2*)(smem + byte) = make_uint2(u0, u1);
    }
    __syncthreads();

    // ---- GEMM: 8 chunks BK=32, 1 barrier/chunk ----
    for (int c = 0; c < 8; ++c) {
        const int p = c & 1;
        if (c < 7) stageW(c + 1, p ^ 1);
        const char* Wp = smem + 131072 + p * 16384;
        bf16x8 a[4], b[8];
        const int qh = ((c * 4 + lg) ^ (lr & 7)) << 4;
        #pragma unroll
        for (int m = 0; m < 4; ++m)
            a[m] = *(const bf16x8*)(smem + (wr * 64 + m * 16 + lr) * 512 + qh);
        #pragma unroll
        for (int f = 0; f < 8; ++f)
            b[f] = *(const bf16x8*)(Wp + (wc * 128 + f * 16 + lr) * 64 + q4);
        #pragma unroll
        for (int m = 0; m < 4; ++m)
            #pragma unroll
            for (int f = 0; f < 8; ++f)
                acc[m][f] = __builtin_amdgcn_mfma_f32_16x16x32_bf16(a[m], b[f], acc[m][f], 0, 0, 0);
        __syncthreads();
    }

    // ---- epilogue: elu+bias -> slice + e1 store + deterministic segment partials ----
    char* slice = smem + wid * 16384;
    const int gR0 = blockRow + wr * 64;
    const int sFirst = gR0 / 127;
    const int bk = 127 - (gR0 - sFirst * 127);     // local row < bk -> seg sFirst
    float s0[8], s1[8];
    #pragma unroll
    for (int f = 0; f < 8; ++f) { s0[f] = 0.f; s1[f] = 0.f; }
    #pragma unroll
    for (int m = 0; m < 4; ++m)
        #pragma unroll
        for (int f = 0; f < 8; ++f) {
            const int col = f * 16 + lr;         // local 0..127
            const int cc = col >> 3;
            #pragma unroll
            for (int r = 0; r < 4; ++r) {
                const int row = m * 16 + lg * 4 + r;   // local 0..63
                float v = eluf(acc[m][f][r] + biasA[f]);
                *(ushort_t*)(slice + row * 256 + ((cc ^ (row & 7)) << 4) + ((col & 7) << 1)) = f2bf(v);
                if (row < bk) s0[f] += v; else s1[f] += v;
            }
        }
    #pragma unroll
    for (int f = 0; f < 8; ++f) {
        s0[f] += __shfl_xor(s0[f], 16); s0[f] += __shfl_xor(s0[f], 32);
        s1[f] += __shfl_xor(s1[f], 16); s1[f] += __shfl_xor(s1[f], 32);
    }
    float* pt = (float*)(smem + 131072);   // [8 waves][2 segs][128 cols]
    if (lg == 0) {
        #pragma unroll
        for (int f = 0; f < 8; ++f) {
            pt[(wid * 2 + 0) * 128 + f * 16 + lr] = s0[f];
            pt[(wid * 2 + 1) * 128 + f * 16 + lr] = s1[f];
        }
    }
    asm volatile("s_waitcnt lgkmcnt(0)" ::: "memory");
    #pragma unroll
    for (int it = 0; it < 16; ++it) {
        const int q = it * 64 + lane;
        const int row = q >> 4, ccp = q & 15;
        bf16x8 v = *(const bf16x8*)(slice + row * 256 + (ccp << 4));
        const int cc = ccp ^ (row & 7);
        const int grow = blockRow + wr * 64 + row;
        *(bf16x8*)(eout + (size_t)grow * 256 + wc * 128 + cc * 8) = v;
    }
    __syncthreads();
    const int S0 = blockRow / 127;
    const int last = (blockRow + 255) / 127;
    const int cnt = last - S0 + 1;                 // 2 or 3
    for (int task = t; task < cnt * 256; task += 512) {
        const int k = task >> 8;
        const int col = task & 255;
        const int sigma = S0 + k;
        const int wcq = col >> 7, c128 = col & 127;
        float sum = 0.f;
        #pragma unroll
        for (int w2r = 0; w2r < 4; ++w2r) {
            int sf = (blockRow + w2r * 64) / 127;
            int jj = sigma - sf;
            if (jj == 0 || jj == 1)
                sum += pt[((w2r * 2 + wcq) * 2 + jj) * 128 + c128];
        }
        const bool startIn = (127 * sigma >= blockRow);
        const bool endIn = (127 * sigma + 127 <= blockRow + 256);
        if (startIn) {
            aggp0[(size_t)sigma * 256 + col] = sum;
            if (endIn) aggp1[(size_t)sigma * 256 + col] = 0.f;
        } else {
            aggp1[(size_t)sigma * 256 + col] = sum;
        }
    }
}

// ---------------- edge2: e1 @ W1x (BK=64) -> +P2r+P2s, elu -> hid2 @ W2e2 -> project ----------------
__global__ __launch_bounds__(512, 2) void edge2_kernel(
    const ushort_t* __restrict__ e1, const float* __restrict__ P2,
    const ushort_t* __restrict__ wBimg,     // img64, 4 chunks
    const ushort_t* __restrict__ wCimg,     // img32, 8 chunks
    const float* __restrict__ bC,
    const float* __restrict__ ow, const float* __restrict__ ob,
    float* __restrict__ out)
{
    extern __shared__ char smem[];
    const int t = threadIdx.x;
    const int wid = t >> 6, lane = t & 63, lr = lane & 15, lg = lane >> 4;
    const int wr = wid >> 1, wc = wid & 1;
    const int q4 = (lg ^ ((lr >> 1) & 3)) << 4;
    const int blockRow = blockIdx.x * 256;

    const int uoff = ((lane & 7) ^ ((lane >> 3) & 7)) * 8;
    const ushort_t* ap[4];
    #pragma unroll
    for (int it = 0; it < 4; ++it) {
        int r = wid * 32 + it * 8 + (lane >> 3);
        ap[it] = e1 + (size_t)(blockRow + r) * 256 + uoff;
    }

    float biasC[8];
    #pragma unroll
    for (int f = 0; f < 8; ++f) biasC[f] = bC[wc * 128 + f * 16 + lr];

    f32x4 acc[4][8];
    #pragma unroll
    for (int m = 0; m < 4; ++m)
        #pragma unroll
        for (int f = 0; f < 8; ++f) acc[m][f] = f32x4{0.f, 0.f, 0.f, 0.f};

    auto stageB64 = [&](int c, int p) {
        const char* src = (const char*)wBimg + (size_t)c * 32768 + wid * 4096 + lane * 16;
        char* dst = smem + 65536 + p * 32768 + wid * 4096;
        #pragma unroll
        for (int it = 0; it < 4; ++it) glds16(dst + it * 1024, src + it * 1024);
    };
    auto stageA64 = [&](int k0, int p) {
        char* dst = smem + p * 32768 + wid * 4096;
        #pragma unroll
        for (int it = 0; it < 4; ++it) glds16(dst + it * 1024, ap[it] + k0);
    };
    auto stageC = [&](int c, int p) {
        const char* src = (const char*)wCimg + (size_t)c * 16384 + wid * 2048 + lane * 16;
        char* dst = smem + 131072 + p * 16384 + wid * 2048;
        glds16(dst, src);
        glds16(dst + 1024, src + 1024);
    };

    // ---- GEMM1: e1 @ W1x, 4 chunks BK=64 ----
    stageB64(0, 0);
    stageA64(0, 0);
    __syncthreads();
    for (int c = 0; c < 4; ++c) {
        const int p = c & 1;
        if (c < 3) { stageB64(c + 1, p ^ 1); stageA64((c + 1) * 64, p ^ 1); }
        else       { stageC(0, 0); }
        const char* Ab = smem + p * 32768;
        const char* Bb = smem + 65536 + p * 32768;
        #pragma unroll
        for (int ks = 0; ks < 2; ++ks) {
            bf16x8 a[4], b[8];
            const int sw = ks * 4 + lg;
            #pragma unroll
            for (int m = 0; m < 4; ++m)
                a[m] = *(const bf16x8*)(Ab + (wr * 64 + m * 16 + lr) * 128 + ((sw ^ (lr & 7)) << 4));
            #pragma unroll
            for (int f = 0; f < 8; ++f)
                b[f] = *(const bf16x8*)(Bb + (wc * 128 + f * 16 + lr) * 128 + ((sw ^ (lr & 7)) << 4));
            #pragma unroll
            for (int m = 0; m < 4; ++m)
                #pragma unroll
                for (int f = 0; f < 8; ++f)
                    acc[m][f] = __builtin_amdgcn_mfma_f32_16x16x32_bf16(a[m], b[f], acc[m][f], 0, 0, 0);
        }
        __syncthreads();
    }

    // ---- transition: hid2 = elu(acc + P2r + P2s) -> Hid (bf16, XOR layout) ----
    #pragma unroll
    for (int m = 0; m < 4; ++m)
        #pragma unroll
        for (int r = 0; r < 4; ++r) {
            const int row = wr * 64 + m * 16 + lg * 4 + r;
            const int rg = blockRow + row;
            const int b = rg / E_; const int e = rg - b * E_;
            const int rcv = e / 127; const int kk = e - rcv * 127;
            const int snd = kk + (kk >= rcv ? 1 : 0);
            const float* pr = P2 + (size_t)(b * N_ + rcv) * 512;
            const float* ps = P2 + (size_t)(b * N_ + snd) * 512 + 256;
            #pragma unroll
            for (int f = 0; f < 8; ++f) {
                const int col = wc * 128 + f * 16 + lr;
                float v = eluf(acc[m][f][r] + pr[col] + ps[col]);
                const int ch = col >> 3;
                *(ushort_t*)(smem + row * 512 + ((ch ^ (row & 7)) << 4) + ((col & 7) << 1)) = f2bf(v);
            }
        }
    #pragma unroll
    for (int m = 0; m < 4; ++m)
        #pragma unroll
        for (int f = 0; f < 8; ++f) acc[m][f] = f32x4{0.f, 0.f, 0.f, 0.f};
    __syncthreads();

    // ---- GEMM2: hid2 @ W2e2, 8 chunks BK=32 ----
    for (int c = 0; c < 8; ++c) {
        const int p = c & 1;
        if (c < 7) stageC(c + 1, p ^ 1);
        const char* Wp = smem + 131072 + p * 16384;
        bf16x8 a[4], b[8];
        const int qh = ((c * 4 + lg) ^ (lr & 7)) << 4;
        #pragma unroll
        for (int m = 0; m < 4; ++m)
            a[m] = *(const bf16x8*)(smem + (wr * 64 + m * 16 + lr) * 512 + qh);
        #pragma unroll
        for (int f = 0; f < 8; ++f)
            b[f] = *(const bf16x8*)(Wp + (wc * 128 + f * 16 + lr) * 64 + q4);
        #pragma unroll
        for (int m = 0; m < 4; ++m)
            #pragma unroll
            for (int f = 0; f < 8; ++f)
                acc[m][f] = __builtin_amdgcn_mfma_f32_16x16x32_bf16(a[m], b[f], acc[m][f], 0, 0, 0);
        __syncthreads();
    }

    // ---- epilogue: fused projection to [row][2] ----
    float ow0[8], ow1[8];
    #pragma unroll
    for (int f = 0; f < 8; ++f) {
        int col = wc * 128 + f * 16 + lr;
        ow0[f] = ow[col * 2 + 0];
        ow1[f] = ow[col * 2 + 1];
    }
    float s0[4][4], s1[4][4];
    #pragma unroll
    for (int m = 0; m < 4; ++m)
        #pragma unroll
        for (int r = 0; r < 4; ++r) { s0[m][r] = 0.f; s1[m][r] = 0.f; }
    #pragma unroll
    for (int m = 0; m < 4; ++m)
        #pragma unroll
        for (int f = 0; f < 8; ++f)
            #pragma unroll
            for (int r = 0; r < 4; ++r) {
                float v = eluf(acc[m][f][r] + biasC[f]);
                s0[m][r] = fmaf(v, ow0[f], s0[m][r]);
                s1[m][r] = fmaf(v, ow1[f], s1[m][r]);
            }
    #pragma unroll
    for (int msk = 1; msk <= 8; msk <<= 1)
        #pragma unroll
        for (int m = 0; m < 4; ++m)
            #pragma unroll
            for (int r = 0; r < 4; ++r) {
                s0[m][r] += __shfl_xor(s0[m][r], msk);
                s1[m][r] += __shfl_xor(s1[m][r], msk);
            }
    float* part = (float*)smem;
    if (lr == 0) {
        #pragma unroll
        for (int m = 0; m < 4; ++m)
            #pragma unroll
            for (int r = 0; r < 4; ++r) {
                const int row = wr * 64 + m * 16 + lg * 4 + r;
                part[(row * 2 + 0) * 2 + wc] = s0[m][r];
                part[(row * 2 + 1) * 2 + wc] = s1[m][r];
            }
    }
    __syncthreads();
    const int row = t >> 1, chn = t & 1;
    float val = part[(row * 2 + chn) * 2 + 0] + part[(row * 2 + chn) * 2 + 1] + ob[chn];
    out[(size_t)(blockRow + row) * 2 + chn] = val;
}

extern "C" void kernel_launch(void* const* d_in, const int* in_sizes, int n_in,
                              void* d_out, int out_size, void* d_ws, size_t ws_size,
                              hipStream_t stream)
{
    const float* x    = (const float*)d_in[0];
    const float* n1w1 = (const float*)d_in[3];
    const float* n1b1 = (const float*)d_in[4];
    const float* n1w2 = (const float*)d_in[5];
    const float* n1b2 = (const float*)d_in[6];
    const float* e1w1 = (const float*)d_in[7];
    const float* e1b1 = (const float*)d_in[8];
    const float* e1w2 = (const float*)d_in[9];
    const float* e1b2 = (const float*)d_in[10];
    const float* n2w1 = (const float*)d_in[11];
    const float* n2b1 = (const float*)d_in[12];
    const float* n2w2 = (const float*)d_in[13];
    const float* n2b2 = (const float*)d_in[14];
    const float* e2w1 = (const float*)d_in[15];
    const float* e2b1 = (const float*)d_in[16];
    const float* e2w2 = (const float*)d_in[17];
    const float* e2b2 = (const float*)d_in[18];
    const float* ow   = (const float*)d_in[19];
    const float* ob   = (const float*)d_in[20];

    char* ws = (char*)d_ws;
    const size_t KB = 1024;
    ushort_t* i_n1w1 = (ushort_t*)(ws + 0 * 128 * KB);
    ushort_t* i_n1w2 = (ushort_t*)(ws + 1 * 128 * KB);
    ushort_t* i_p1r  = (ushort_t*)(ws + 2 * 128 * KB);
    ushort_t* i_p1s  = (ushort_t*)(ws + 3 * 128 * KB);
    ushort_t* i_n2w1 = (ushort_t*)(ws + 4 * 128 * KB);
    ushort_t* i_n2w2 = (ushort_t*)(ws + 5 * 128 * KB);
    ushort_t* i_p2r  = (ushort_t*)(ws + 6 * 128 * KB);
    ushort_t* i_p2s  = (ushort_t*)(ws + 7 * 128 * KB);
    ushort_t* wB     = (ushort_t*)(ws + 8 * 128 * KB);
    ushort_t* wA     = (ushort_t*)(ws + 9 * 128 * KB);
    ushort_t* wC     = (ushort_t*)(ws + 10 * 128 * KB);
    float*    P1    = (float*)(ws + 1536 * KB);            // 2MB [1024][512]
    float*    P2    = (float*)(ws + 1536 * KB + (2u << 20));
    float*    aggp0 = (float*)(ws + 1536 * KB + (4u << 20));
    float*    aggp1 = (float*)(ws + 1536 * KB + (5u << 20));
    ushort_t* e1    = (ushort_t*)(ws + 1536 * KB + (6u << 20)); // 66.6MB

    float* out = (float*)d_out;

    hipFuncSetAttribute((const void*)node_fused<false>,
                        hipFuncAttributeMaxDynamicSharedMemorySize, 147456);
    hipFuncSetAttribute((const void*)node_fused<true>,
                        hipFuncAttributeMaxDynamicSharedMemorySize, 147456);
    hipFuncSetAttribute((const void*)edge1_kernel,
                        hipFuncAttributeMaxDynamicSharedMemorySize, 163840);
    hipFuncSetAttribute((const void*)edge2_kernel,
                        hipFuncAttributeMaxDynamicSharedMemorySize, 163840);

    wprep_all<<<2816, 256, 0, stream>>>(
        n1w1, i_n1w1, n1w2, i_n1w2, e1w1, i_p1r, i_p1s,
        n2w1, i_n2w1, n2w2, i_n2w2, e2w1, i_p2r, i_p2s, wB,
        e1w2, wA, e2w2, wC);

    node_fused<false><<<32, 256, 147456, stream>>>(
        x, nullptr, i_n1w1, n1b1, i_n1w2, n1b2, i_p1r, i_p1s, e1b1, P1);

    edge1_kernel<<<BE / 256, 512, 163840, stream>>>(P1, wA, e1b2, e1, aggp0, aggp1);

    node_fused<true><<<32, 256, 147456, stream>>>(
        aggp0, aggp1, i_n2w1, n2b1, i_n2w2, n2b2, i_p2r, i_p2s, e2b1, P2);

    edge2_kernel<<<BE / 256, 512, 163840, stream>>>(
        e1, P2, wB, wC, e2b2, ow, ob, out);
}